// Round 2
// baseline (230.755 us; speedup 1.0000x reference)
//
#include <hip/hip_runtime.h>

#define B_ 8
#define N_ 8192
#define S_ 2048
#define D_ 256
#define EPS_ 1e-8f
#define TILE_Q 64
#define NCH 4
#define CHUNK (S_ / NCH) /* 512 */

// Branchless stable top-3 insert using the med3 sorting network.
// Sorted invariant d0<=d1<=d2. Strict '<' => incumbent (earlier index) wins
// ties, matching jax.lax.top_k stability.
// 12 VALU: 3 v_cmp + v_min/v_med3/v_max/v_min + 5 v_cndmask.
__device__ __forceinline__ void insert3(float dd, int s,
                                        float& d0, float& d1, float& d2,
                                        int& i0, int& i1, int& i2) {
    bool ca = dd < d0;
    bool cb = dd < d1;
    bool cc = dd < d2;
    // indices: consume old i0/i1 before overwrite
    int i2n = cb ? i1 : (cc ? s : i2);
    int i1n = ca ? i0 : (cb ? s : i1);
    int i0n = ca ? s : i0;
    d2 = fminf(d2, fmaxf(d1, dd));
    d1 = __builtin_amdgcn_fmed3f(d0, d1, dd);
    d0 = fminf(d0, dd);
    i0 = i0n; i1 = i1n; i2 = i2n;
}

__global__ __launch_bounds__(256) void fp_interp_kernel(
    const float* __restrict__ xyz1,     // [B,3,N]
    const float* __restrict__ xyz2,     // [B,3,S]
    const float* __restrict__ points2,  // [B,S,D]
    float* __restrict__ out)            // [B,N,D]
{
    __shared__ float  s_pd[NCH][3][TILE_Q];  // partial top-3 dists
    __shared__ int    s_pi[NCH][3][TILE_Q];  // partial top-3 idx
    __shared__ float  s_w[3][TILE_Q];        // final weights
    __shared__ int    s_idx[3][TILE_Q];      // final idx

    const int blocksPerBatch = N_ / TILE_Q;  // 128
    const int b  = blockIdx.x / blocksPerBatch;
    const int n0 = (blockIdx.x % blocksPerBatch) * TILE_Q;
    const int t = threadIdx.x;
    const int wave = t >> 6, lane = t & 63;

    // Phase A: wave w scans candidate chunk w for all 64 queries (lane<->query).
    // Candidate coords are wave-uniform (loop var) -> compiler scalarizes the
    // loads to s_load on the SMEM pipe; VALU does only distance + select.
    const int n = n0 + lane;
    const float* x1 = xyz1 + (size_t)b * 3 * N_;
    const float ax = x1[n], ay = x1[N_ + n], az = x1[2 * N_ + n];

    const float* x2x = xyz2 + (size_t)b * 3 * S_;
    const float* x2y = x2x + S_;
    const float* x2z = x2x + 2 * S_;

    float d0 = __builtin_inff(), d1 = __builtin_inff(), d2 = __builtin_inff();
    int i0 = 0, i1 = 0, i2 = 0;
    const int sbeg = wave * CHUNK;
    #pragma unroll 8
    for (int s = sbeg; s < sbeg + CHUNK; ++s) {
        // direct squared distance: 3 sub + 1 mul + 2 fma (more accurate than
        // the |a|^2+|b|^2-2ab expansion -> fewer selection flips vs np ref)
        float dx = ax - x2x[s];
        float dy = ay - x2y[s];
        float dz = az - x2z[s];
        float dd = fmaf(dx, dx, fmaf(dy, dy, dz * dz));
        insert3(dd, s, d0, d1, d2, i0, i1, i2);
    }
    s_pd[wave][0][lane] = d0; s_pd[wave][1][lane] = d1; s_pd[wave][2][lane] = d2;
    s_pi[wave][0][lane] = i0; s_pi[wave][1][lane] = i1; s_pi[wave][2][lane] = i2;
    __syncthreads();

    // Phase B: merge 4 chunk-triples per query (chunk order => index-stable).
    if (t < TILE_Q) {
        float e0 = __builtin_inff(), e1 = __builtin_inff(), e2 = __builtin_inff();
        int j0 = 0, j1 = 0, j2 = 0;
        #pragma unroll
        for (int c = 0; c < NCH; ++c) {
            #pragma unroll
            for (int k = 0; k < 3; ++k)
                insert3(s_pd[c][k][t], s_pi[c][k][t], e0, e1, e2, j0, j1, j2);
        }
        // weights with numpy-matching op order
        float r0 = __fdiv_rn(1.0f, __fadd_rn(e0, EPS_));
        float r1 = __fdiv_rn(1.0f, __fadd_rn(e1, EPS_));
        float r2 = __fdiv_rn(1.0f, __fadd_rn(e2, EPS_));
        float rs = __fadd_rn(__fadd_rn(r0, r1), r2);
        s_w[0][t] = __fdiv_rn(r0, rs);
        s_w[1][t] = __fdiv_rn(r1, rs);
        s_w[2][t] = __fdiv_rn(r2, rs);
        s_idx[0][t] = j0; s_idx[1][t] = j1; s_idx[2][t] = j2;
    }
    __syncthreads();

    // Phase C: gather + weighted sum. One wave per query row; 64 lanes x float4
    // covers D=256. Reads hit L2 (points2 slice is 2MB/batch).
    const float* p2 = points2 + (size_t)b * S_ * D_;
    float* op = out + ((size_t)b * N_ + n0) * D_;
    for (int q = wave; q < TILE_Q; q += 4) {
        float w0 = s_w[0][q], w1 = s_w[1][q], w2 = s_w[2][q];
        const float4* f0 = (const float4*)(p2 + (size_t)s_idx[0][q] * D_) + lane;
        const float4* f1 = (const float4*)(p2 + (size_t)s_idx[1][q] * D_) + lane;
        const float4* f2 = (const float4*)(p2 + (size_t)s_idx[2][q] * D_) + lane;
        float4 a0 = *f0, a1 = *f1, a2 = *f2;
        float4 r;
        r.x = w0 * a0.x + w1 * a1.x + w2 * a2.x;
        r.y = w0 * a0.y + w1 * a1.y + w2 * a2.y;
        r.z = w0 * a0.z + w1 * a1.z + w2 * a2.z;
        r.w = w0 * a0.w + w1 * a1.w + w2 * a2.w;
        *((float4*)(op + (size_t)q * D_) + lane) = r;
    }
}

extern "C" void kernel_launch(void* const* d_in, const int* in_sizes, int n_in,
                              void* d_out, int out_size, void* d_ws, size_t ws_size,
                              hipStream_t stream) {
    const float* xyz1    = (const float*)d_in[0];
    const float* xyz2    = (const float*)d_in[1];
    // d_in[2] = points1 is unused by the reference output.
    const float* points2 = (const float*)d_in[3];
    float* out = (float*)d_out;

    dim3 grid(B_ * (N_ / TILE_Q));  // 1024 blocks
    dim3 block(256);
    fp_interp_kernel<<<grid, block, 0, stream>>>(xyz1, xyz2, points2, out);
}

// Round 3
// 185.477 us; speedup vs baseline: 1.2441x; 1.2441x over previous
//
#include <hip/hip_runtime.h>

#define B_ 8
#define N_ 8192
#define S_ 2048
#define D_ 256
#define EPS_ 1e-8f
#define TILE_Q 64
#define NTHR 512
#define NCH 8
#define CHUNK (S_ / NCH) /* 256 */

struct F3 { float x, y, z; };  // 12 B -> keeps LDS at 24 KB for the xyz tile

// Branchless stable top-3 insert, med3 network. Sorted invariant d0<=d1<=d2.
// Strict '<' => incumbent (earlier index) wins ties, matching jax.lax.top_k.
__device__ __forceinline__ void insert3(float dd, int s,
                                        float& d0, float& d1, float& d2,
                                        int& i0, int& i1, int& i2) {
    bool ca = dd < d0;
    bool cb = dd < d1;
    bool cc = dd < d2;
    int i2n = cb ? i1 : (cc ? s : i2);
    int i1n = ca ? i0 : (cb ? s : i1);
    int i0n = ca ? s : i0;
    d2 = fminf(d2, fmaxf(d1, dd));
    d1 = __builtin_amdgcn_fmed3f(d0, d1, dd);
    d0 = fminf(d0, dd);
    i0 = i0n; i1 = i1n; i2 = i2n;
}

__global__ __launch_bounds__(NTHR) void fp_interp_kernel(
    const float* __restrict__ xyz1,     // [B,3,N]
    const float* __restrict__ xyz2,     // [B,3,S]
    const float* __restrict__ points2,  // [B,S,D]
    float* __restrict__ out)            // [B,N,D]
{
    __shared__ F3    s_xyz[S_];              // 24 KB candidate coords
    __shared__ float s_pd[NCH][3][TILE_Q];   // partial top-3 dists (6 KB)
    __shared__ int   s_pi[NCH][3][TILE_Q];   // partial top-3 idx   (6 KB)
    __shared__ float s_w[3][TILE_Q];
    __shared__ int   s_idx[3][TILE_Q];

    const int blocksPerBatch = N_ / TILE_Q;  // 128
    const int b  = blockIdx.x / blocksPerBatch;
    const int n0 = (blockIdx.x % blocksPerBatch) * TILE_Q;
    const int t = threadIdx.x;
    const int wave = t >> 6, lane = t & 63;

    // Stage xyz2 for this batch into LDS (coalesced global, stride-1 writes).
    const float* x2 = xyz2 + (size_t)b * 3 * S_;
    for (int s = t; s < S_; s += NTHR) {
        F3 c; c.x = x2[s]; c.y = x2[S_ + s]; c.z = x2[2 * S_ + s];
        s_xyz[s] = c;
    }
    __syncthreads();

    // Phase A: wave w scans candidate chunk w for all 64 queries (lane<->query).
    // s_xyz[s] is wave-uniform -> LDS broadcast (0 conflicts, measured R1).
    const int n = n0 + lane;
    const float* x1 = xyz1 + (size_t)b * 3 * N_;
    const float ax = x1[n], ay = x1[N_ + n], az = x1[2 * N_ + n];

    float d0 = __builtin_inff(), d1 = __builtin_inff(), d2 = __builtin_inff();
    int i0 = 0, i1 = 0, i2 = 0;
    const int sbeg = wave * CHUNK;
    #pragma unroll 8
    for (int s = sbeg; s < sbeg + CHUNK; ++s) {
        F3 c = s_xyz[s];
        float dx = ax - c.x;
        float dy = ay - c.y;
        float dz = az - c.z;
        float dd = fmaf(dx, dx, fmaf(dy, dy, dz * dz));
        insert3(dd, s, d0, d1, d2, i0, i1, i2);
    }
    s_pd[wave][0][lane] = d0; s_pd[wave][1][lane] = d1; s_pd[wave][2][lane] = d2;
    s_pi[wave][0][lane] = i0; s_pi[wave][1][lane] = i1; s_pi[wave][2][lane] = i2;
    __syncthreads();

    // Phase B: merge 8 chunk-triples per query (chunk order => index-stable).
    if (t < TILE_Q) {
        float e0 = __builtin_inff(), e1 = __builtin_inff(), e2 = __builtin_inff();
        int j0 = 0, j1 = 0, j2 = 0;
        #pragma unroll
        for (int c = 0; c < NCH; ++c) {
            #pragma unroll
            for (int k = 0; k < 3; ++k)
                insert3(s_pd[c][k][t], s_pi[c][k][t], e0, e1, e2, j0, j1, j2);
        }
        float r0 = __fdiv_rn(1.0f, __fadd_rn(e0, EPS_));
        float r1 = __fdiv_rn(1.0f, __fadd_rn(e1, EPS_));
        float r2 = __fdiv_rn(1.0f, __fadd_rn(e2, EPS_));
        float rs = __fadd_rn(__fadd_rn(r0, r1), r2);
        s_w[0][t] = __fdiv_rn(r0, rs);
        s_w[1][t] = __fdiv_rn(r1, rs);
        s_w[2][t] = __fdiv_rn(r2, rs);
        s_idx[0][t] = j0; s_idx[1][t] = j1; s_idx[2][t] = j2;
    }
    __syncthreads();

    // Phase C: gather + weighted sum. One wave per query row; 64 lanes x float4
    // covers D=256. points2 slice is 2 MB/batch -> L2-resident.
    const float* p2 = points2 + (size_t)b * S_ * D_;
    float* op = out + ((size_t)b * N_ + n0) * D_;
    for (int q = wave; q < TILE_Q; q += NCH) {
        float w0 = s_w[0][q], w1 = s_w[1][q], w2 = s_w[2][q];
        const float4* f0 = (const float4*)(p2 + (size_t)s_idx[0][q] * D_) + lane;
        const float4* f1 = (const float4*)(p2 + (size_t)s_idx[1][q] * D_) + lane;
        const float4* f2 = (const float4*)(p2 + (size_t)s_idx[2][q] * D_) + lane;
        float4 a0 = *f0, a1 = *f1, a2 = *f2;
        float4 r;
        r.x = w0 * a0.x + w1 * a1.x + w2 * a2.x;
        r.y = w0 * a0.y + w1 * a1.y + w2 * a2.y;
        r.z = w0 * a0.z + w1 * a1.z + w2 * a2.z;
        r.w = w0 * a0.w + w1 * a1.w + w2 * a2.w;
        *((float4*)(op + (size_t)q * D_) + lane) = r;
    }
}

extern "C" void kernel_launch(void* const* d_in, const int* in_sizes, int n_in,
                              void* d_out, int out_size, void* d_ws, size_t ws_size,
                              hipStream_t stream) {
    const float* xyz1    = (const float*)d_in[0];
    const float* xyz2    = (const float*)d_in[1];
    // d_in[2] = points1 is unused by the reference output.
    const float* points2 = (const float*)d_in[3];
    float* out = (float*)d_out;

    dim3 grid(B_ * (N_ / TILE_Q));  // 1024 blocks, 4 per CU at 512 thr
    dim3 block(NTHR);
    fp_interp_kernel<<<grid, block, 0, stream>>>(xyz1, xyz2, points2, out);
}